// Round 9
// baseline (544.531 us; speedup 1.0000x reference)
//
#include <hip/hip_runtime.h>
#include <hip/hip_bf16.h>

typedef __attribute__((ext_vector_type(4))) float f32x4;
typedef __attribute__((ext_vector_type(8))) short bf16x8;
typedef unsigned int   u32;
typedef unsigned short u16;

#define DPAD 8
#define B_   8
#define C_   512
#define T_   8192
#define S_   256

// workspace byte offsets
#define OFF_WBIG 0u          // u16[1024*1024]      = 2,097,152 B
#define OFF_W2   2097152u    // u16[768*512]        =   786,432 B
#define OFF_B1   2883584u    // float[1024]
#define OFF_B2   2887680u    // float[768]
#define OFF_XT   2891776u    // u16[8*(8192+8)*512] = 67,174,400 B
#define OFF_ZT   70066176u   // u16[8*8192*512]     = 67,108,864 B

__device__ __forceinline__ u16 f2bf(float f) {
  u32 u = __builtin_bit_cast(u32, f);
  u += 0x7FFFu + ((u >> 16) & 1u);
  return (u16)(u >> 16);
}
__device__ __forceinline__ float sigm_(float x) { return 1.0f / (1.0f + __expf(-x)); }
__device__ __forceinline__ float tanh_(float x) { return 2.0f / (1.0f + __expf(-2.0f * x)) - 1.0f; }

__device__ __forceinline__ void gload_lds16(const void* g, void* l) {
  __builtin_amdgcn_global_load_lds(
      (const __attribute__((address_space(1))) void*)g,
      (__attribute__((address_space(3))) void*)l, 16, 0, 0);
}

// ---------------- pack weights / biases, zero Xt pad rows ----------------
__global__ void pack_kernel(const float* __restrict__ fw, const float* __restrict__ fb,
                            const float* __restrict__ gw, const float* __restrict__ gb,
                            const float* __restrict__ rw, const float* __restrict__ rb,
                            const float* __restrict__ sw, const float* __restrict__ sb,
                            u16* __restrict__ Wbig, u16* __restrict__ W2,
                            float* __restrict__ b1, float* __restrict__ b2,
                            u16* __restrict__ Xt)
{
  int idx = blockIdx.x * 256 + threadIdx.x;
  if (idx < 1048576) {                    // Wbig[row][k], row 2i=filter i, 2i+1=gate i
    int row = idx >> 10, k = idx & 1023;  // k<512: tap1 (x[t]); k>=512: tap0 (x[t-d])
    int i = row >> 1;
    const float* src = (row & 1) ? gw : fw;
    float v = src[((i << 9) + (k & 511)) * 2 + ((k < 512) ? 1 : 0)];
    Wbig[idx] = f2bf(v);
    return;
  }
  idx -= 1048576;
  if (idx < 393216) {                     // W2[r][k]: r<512 res, else skip
    int r = idx >> 9, k = idx & 511;
    float v = (r < 512) ? rw[(r << 9) + k] : sw[((r - 512) << 9) + k];
    W2[idx] = f2bf(v);
    return;
  }
  idx -= 393216;
  if (idx < 1024) { b1[idx] = (idx & 1) ? gb[idx >> 1] : fb[idx >> 1]; return; }
  idx -= 1024;
  if (idx < 768) { b2[idx] = (idx < 512) ? rb[idx] : sb[idx - 512]; return; }
  idx -= 768;
  if (idx < B_ * DPAD * C_) {             // zero causal pad rows of Xt
    int b = idx >> 12;                    // DPAD*C_ = 4096
    int rest = idx & 4095;
    Xt[(size_t)b * (T_ + DPAD) * C_ + rest] = 0;
  }
}

// ---------------- x [B][C][T] f32 -> Xt [B][DPAD+T][C] bf16 ----------------
__global__ __launch_bounds__(256) void transpose_kernel(const float* __restrict__ x,
                                                        u16* __restrict__ Xt)
{
  __shared__ float tile[64][65];
  int bid = blockIdx.x;
  int ct = bid & 7, tt = (bid >> 3) & 127, b = bid >> 10;
  int w = threadIdx.x >> 6, ln = threadIdx.x & 63;
  const float* xp = x + ((size_t)(b * C_ + ct * 64)) * T_ + tt * 64;
#pragma unroll
  for (int r = 0; r < 16; ++r) {
    int cl = r * 4 + w;
    tile[cl][ln] = xp[(size_t)cl * T_ + ln];
  }
  __syncthreads();
  u16* op = Xt + ((size_t)b * (T_ + DPAD) + DPAD + tt * 64) * C_ + ct * 64;
#pragma unroll
  for (int r = 0; r < 16; ++r) {
    int tl = r * 4 + w;
    op[(size_t)tl * C_ + ln] = f2bf(tile[ln][tl]);
  }
}

// ---------------- GEMM1: 256x256, 8 waves, NO LDS / NO BARRIERS ----------------
// Both operands are fragment-shaped in memory (W row-major [m][k]; Xt [t][c]):
// each bf16x8 A/B fragment is a single global_load_dwordx4 at row*stride+k.
// Waves free-run; register double-buffer by 32-k slice; 32 independent-acc
// MFMAs per slice (no RAW); compiler inserts vmcnt for register deps.
__global__ __launch_bounds__(512, 2) void gemm1_kernel(
    const u16* __restrict__ W, const u16* __restrict__ Xt,
    const float* __restrict__ b1, u16* __restrict__ Zt,
    const int* __restrict__ dptr)
{
  const int dcap = *dptr;
  const int tid = threadIdx.x;
  const int lane = tid & 63, wave = tid >> 6;
  const int wm = wave >> 2, wn = wave & 3;    // 2 x 4 waves -> 128x64 per wave
  const int lp = lane & 15, lg = lane >> 4;

  const int bid = blockIdx.x;
  const int xcd = bid & 7;
  const int idx = bid >> 3;                 // 0..127 within XCD
  const int mt  = idx & 3;                  // m fastest -> B-panel L2 reuse
  const int nt  = (xcd << 5) | (idx >> 2);  // n-tile 0..255
  const int m0  = mt * 256;
  const int n0g = nt * 256;
  const int b = n0g >> 13, t0 = n0g & (T_ - 1);
  const size_t xtb = (size_t)b * (T_ + DPAD) * C_;

  f32x4 acc[8][4];
#pragma unroll
  for (int i = 0; i < 8; ++i)
#pragma unroll
    for (int j = 0; j < 4; ++j) acc[i][j] = (f32x4){0.f, 0.f, 0.f, 0.f};

  // per-wave fragment base rows (element units)
  const u16* const aBase = W + (size_t)(m0 + wm * 128 + lp) * 1024 + lg * 8;
  const u16* const bBase = Xt + xtb + (size_t)(DPAD + t0 + wn * 64 + lp) * C_ + lg * 8;

  // g = global 32-k slice index, 0..31. k = g*32; tap0 (k>=512) reads rows t-d.
#define LOADS(g_, Ab, Bb) do {                                                 \
    const int kk_  = (g_) * 32;                                                \
    const int col_ = kk_ & 511;                                                \
    const int rsh_ = (kk_ >= 512) ? dcap : 0;                                  \
    const u16* pa_ = aBase + kk_;                                              \
    const u16* pb_ = bBase + col_ - (size_t)rsh_ * C_;                         \
    _Pragma("unroll") for (int i_ = 0; i_ < 8; ++i_)                           \
      Ab[i_] = *(const bf16x8*)(pa_ + (size_t)i_ * 16 * 1024);                 \
    _Pragma("unroll") for (int j_ = 0; j_ < 4; ++j_)                           \
      Bb[j_] = *(const bf16x8*)(pb_ + (size_t)j_ * 16 * C_);                   \
  } while (0)

#define MM(Ab, Bb) do {                                                        \
    _Pragma("unroll") for (int i_ = 0; i_ < 8; ++i_)                           \
      _Pragma("unroll") for (int j_ = 0; j_ < 4; ++j_)                         \
        acc[i_][j_] = __builtin_amdgcn_mfma_f32_16x16x32_bf16(Ab[i_], Bb[j_], acc[i_][j_], 0, 0, 0); \
  } while (0)

  bf16x8 A0[8], B0[4], A1[8], B1[4];
  LOADS(0, A0, B0);
#pragma unroll 2
  for (int g = 0; g < 31; ++g) {
    if (g & 1) { LOADS(g + 1, A0, B0); } else { LOADS(g + 1, A1, B1); }
    if (g & 1) { MM(A1, B1); } else { MM(A0, B0); }
  }
  MM(A1, B1);   // g = 31 (loaded during g = 30)

  // epilogue: rows R..R+3 = (filter c0, gate c0, filter c0+1, gate c0+1)
  const int g4 = lane >> 4, p = lane & 15;
#pragma unroll
  for (int i = 0; i < 8; ++i) {
    const int R = m0 + wm * 128 + i * 16 + (g4 << 2);
    const float bi0 = b1[R], bi1 = b1[R + 1], bi2 = b1[R + 2], bi3 = b1[R + 3];
    const int c0 = R >> 1;
#pragma unroll
    for (int j = 0; j < 4; ++j) {
      const int ttc = t0 + wn * 64 + j * 16 + p;
      f32x4 v = acc[i][j];
      float z0 = tanh_(v[0] + bi0) * sigm_(v[1] + bi1);
      float z1 = tanh_(v[2] + bi2) * sigm_(v[3] + bi3);
      u32 pk = (u32)f2bf(z0) | ((u32)f2bf(z1) << 16);
      *(u32*)(Zt + (size_t)(b * T_ + ttc) * C_ + c0) = pk;
    }
  }
#undef LOADS
#undef MM
}

// ---------------- GEMM2: [768x512] x z + residual/skip epilogue ----------------
// k-loop: proven drain structure. Epilogue: per-wave LDS transpose in disjoint
// region -> f32x4 coalesced x-loads / out-stores along t.
__global__ __launch_bounds__(256, 4) void gemm2_kernel(
    const u16* __restrict__ W2, const u16* __restrict__ Zt,
    const float* __restrict__ b2, const float* __restrict__ x,
    float* __restrict__ out)
{
  __shared__ __align__(16) u16 As[128 * 32];
  __shared__ __align__(16) u16 Bs[128 * 32];
  __shared__ __align__(16) float fstall[4 * 1088];   // 4 waves x 16x68 padded
  const int tid = threadIdx.x;
  const int lane = tid & 63, wave = tid >> 6;
  const int wm = wave >> 1, wn = wave & 1;

  const int bid = blockIdx.x;
  const int xcd = bid & 7;
  const int idx = bid >> 3;            // 0..383
  const int mt  = idx % 6;
  const int nt  = (xcd << 6) + idx / 6;
  const int m0 = mt * 128;
  const int n0g = nt * 128;
  const int b = n0g >> 13, t0 = n0g & (T_ - 1);
  const int srow = tid >> 2;
  const int skk  = (tid & 3) * 8;

  f32x4 acc[4][4];
#pragma unroll
  for (int i = 0; i < 4; ++i)
#pragma unroll
    for (int j = 0; j < 4; ++j) acc[i][j] = (f32x4){0.f, 0.f, 0.f, 0.f};

  const int aoff = (wm * 64 + (lane & 15)) * 32 + (lane >> 4) * 8;
  const int boff = (wn * 64 + (lane & 15)) * 32 + (lane >> 4) * 8;
  const size_t ztb = (size_t)b * T_ * C_;

  for (int kc = 0; kc < 16; ++kc) {
    const int k = kc * 32 + skk;        // 0..511
    const u16* gA = W2 + (size_t)(m0 + srow) * 512 + k;
    const u16* gB = Zt + ztb + (size_t)(t0 + srow) * C_ + k;
    gload_lds16(gA,            As + tid * 8);
    gload_lds16(gA + 64 * 512, As + 2048 + tid * 8);
    gload_lds16(gB,            Bs + tid * 8);
    gload_lds16(gB + 64 * C_,  Bs + 2048 + tid * 8);
    asm volatile("s_waitcnt vmcnt(0)" ::: "memory");
    __syncthreads();
    bf16x8 af[4], bfr[4];
#pragma unroll
    for (int i = 0; i < 4; ++i) af[i]  = *(const bf16x8*)(As + aoff + i * 512);
#pragma unroll
    for (int j = 0; j < 4; ++j) bfr[j] = *(const bf16x8*)(Bs + boff + j * 512);
#pragma unroll
    for (int i = 0; i < 4; ++i)
#pragma unroll
      for (int j = 0; j < 4; ++j)
        acc[i][j] = __builtin_amdgcn_mfma_f32_16x16x32_bf16(af[i], bfr[j], acc[i][j], 0, 0, 0);
    __syncthreads();
  }

  // ---- coalesced epilogue: per-wave private LDS transpose of 16x64 quadrants ----
  float* const fst = fstall + wave * 1088;         // 16 rows x 68 (padded)
  const int g = lane >> 4, p = lane & 15;
  const bool isres = (m0 < 512);

#pragma unroll
  for (int i = 0; i < 4; ++i) {
#pragma unroll
    for (int j = 0; j < 4; ++j)
#pragma unroll
      for (int r = 0; r < 4; ++r)
        fst[(g * 4 + r) * 68 + j * 16 + p] = acc[i][j][r];
#pragma unroll
    for (int q = 0; q < 4; ++q) {
      const int lrow = q * 4 + g;                  // 0..15
      const int row = m0 + wm * 64 + i * 16 + lrow;
      const int t = t0 + wn * 64 + p * 4;
      f32x4 v = *(const f32x4*)&fst[lrow * 68 + p * 4];
      const float bias = b2[row];
      f32x4 res;
      if (isres) {
        const size_t o = ((size_t)(b * 512 + row)) * T_ + t;
        f32x4 xv = *(const f32x4*)(x + o);
#pragma unroll
        for (int e = 0; e < 4; ++e)
          res[e] = (xv[e] + v[e] + bias) * 0.70710678118654752f;
        *(f32x4*)(out + o) = res;
      } else {
        const size_t o = (size_t)33554432 + ((size_t)(b * 256 + (row - 512))) * T_ + t;
#pragma unroll
        for (int e = 0; e < 4; ++e)
          res[e] = v[e] + bias;
        *(f32x4*)(out + o) = res;
      }
    }
  }
}

extern "C" void kernel_launch(void* const* d_in, const int* in_sizes, int n_in,
                              void* d_out, int out_size, void* d_ws, size_t ws_size,
                              hipStream_t stream) {
  const float* x  = (const float*)d_in[0];
  const float* fw = (const float*)d_in[1];
  const float* fb = (const float*)d_in[2];
  const float* gw = (const float*)d_in[3];
  const float* gb = (const float*)d_in[4];
  const float* rw = (const float*)d_in[5];
  const float* rb = (const float*)d_in[6];
  const float* sw = (const float*)d_in[7];
  const float* sb = (const float*)d_in[8];
  const int* dil  = (const int*)d_in[9];

  char* ws = (char*)d_ws;
  u16*   Wbig = (u16*)(ws + OFF_WBIG);
  u16*   W2   = (u16*)(ws + OFF_W2);
  float* b1   = (float*)(ws + OFF_B1);
  float* b2   = (float*)(ws + OFF_B2);
  u16*   Xt   = (u16*)(ws + OFF_XT);
  u16*   Zt   = (u16*)(ws + OFF_ZT);
  float* out  = (float*)d_out;

  hipLaunchKernelGGL(pack_kernel, dim3(5767), dim3(256), 0, stream,
                     fw, fb, gw, gb, rw, rb, sw, sb, Wbig, W2, b1, b2, Xt);
  hipLaunchKernelGGL(transpose_kernel, dim3(8192), dim3(256), 0, stream, x, Xt);
  hipLaunchKernelGGL(gemm1_kernel, dim3(1024), dim3(512), 0, stream, Wbig, Xt, b1, Zt, dil);
  hipLaunchKernelGGL(gemm2_kernel, dim3(3072), dim3(256), 0, stream, W2, Zt, b2, x, out);
}

// Round 10
// 307.384 us; speedup vs baseline: 1.7715x; 1.7715x over previous
//
#include <hip/hip_runtime.h>
#include <hip/hip_bf16.h>

typedef __attribute__((ext_vector_type(4))) float f32x4;
typedef __attribute__((ext_vector_type(8))) short bf16x8;
typedef unsigned int   u32;
typedef unsigned short u16;

#define DPAD 8
#define B_   8
#define C_   512
#define T_   8192
#define S_   256

// workspace byte offsets
#define OFF_WBIG 0u          // u16[1024*1024]      = 2,097,152 B
#define OFF_W2   2097152u    // u16[768*512]        =   786,432 B
#define OFF_B1   2883584u    // float[1024]
#define OFF_B2   2887680u    // float[768]
#define OFF_XT   2891776u    // u16[8*(8192+8)*512] = 67,174,400 B
#define OFF_ZT   70066176u   // u16[8*8192*512]     = 67,108,864 B

__device__ __forceinline__ u16 f2bf(float f) {
  u32 u = __builtin_bit_cast(u32, f);
  u += 0x7FFFu + ((u >> 16) & 1u);
  return (u16)(u >> 16);
}
__device__ __forceinline__ float sigm_(float x) { return 1.0f / (1.0f + __expf(-x)); }
__device__ __forceinline__ float tanh_(float x) { return 2.0f / (1.0f + __expf(-2.0f * x)) - 1.0f; }

__device__ __forceinline__ void gload_lds16(const void* g, void* l) {
  __builtin_amdgcn_global_load_lds(
      (const __attribute__((address_space(1))) void*)g,
      (__attribute__((address_space(3))) void*)l, 16, 0, 0);
}

// ---------------- pack weights / biases, zero Xt pad rows ----------------
__global__ void pack_kernel(const float* __restrict__ fw, const float* __restrict__ fb,
                            const float* __restrict__ gw, const float* __restrict__ gb,
                            const float* __restrict__ rw, const float* __restrict__ rb,
                            const float* __restrict__ sw, const float* __restrict__ sb,
                            u16* __restrict__ Wbig, u16* __restrict__ W2,
                            float* __restrict__ b1, float* __restrict__ b2,
                            u16* __restrict__ Xt)
{
  int idx = blockIdx.x * 256 + threadIdx.x;
  if (idx < 1048576) {                    // Wbig[row][k], row 2i=filter i, 2i+1=gate i
    int row = idx >> 10, k = idx & 1023;  // k<512: tap1 (x[t]); k>=512: tap0 (x[t-d])
    int i = row >> 1;
    const float* src = (row & 1) ? gw : fw;
    float v = src[((i << 9) + (k & 511)) * 2 + ((k < 512) ? 1 : 0)];
    Wbig[idx] = f2bf(v);
    return;
  }
  idx -= 1048576;
  if (idx < 393216) {                     // W2[r][k]: r<512 res, else skip
    int r = idx >> 9, k = idx & 511;
    float v = (r < 512) ? rw[(r << 9) + k] : sw[((r - 512) << 9) + k];
    W2[idx] = f2bf(v);
    return;
  }
  idx -= 393216;
  if (idx < 1024) { b1[idx] = (idx & 1) ? gb[idx >> 1] : fb[idx >> 1]; return; }
  idx -= 1024;
  if (idx < 768) { b2[idx] = (idx < 512) ? rb[idx] : sb[idx - 512]; return; }
  idx -= 768;
  if (idx < B_ * DPAD * C_) {             // zero causal pad rows of Xt
    int b = idx >> 12;                    // DPAD*C_ = 4096
    int rest = idx & 4095;
    Xt[(size_t)b * (T_ + DPAD) * C_ + rest] = 0;
  }
}

// ---------------- x [B][C][T] f32 -> Xt [B][DPAD+T][C] bf16 ----------------
__global__ __launch_bounds__(256) void transpose_kernel(const float* __restrict__ x,
                                                        u16* __restrict__ Xt)
{
  __shared__ float tile[64][65];
  int bid = blockIdx.x;
  int ct = bid & 7, tt = (bid >> 3) & 127, b = bid >> 10;
  int w = threadIdx.x >> 6, ln = threadIdx.x & 63;
  const float* xp = x + ((size_t)(b * C_ + ct * 64)) * T_ + tt * 64;
#pragma unroll
  for (int r = 0; r < 16; ++r) {
    int cl = r * 4 + w;
    tile[cl][ln] = xp[(size_t)cl * T_ + ln];
  }
  __syncthreads();
  u16* op = Xt + ((size_t)b * (T_ + DPAD) + DPAD + tt * 64) * C_ + ct * 64;
#pragma unroll
  for (int r = 0; r < 16; ++r) {
    int tl = r * 4 + w;
    op[(size_t)tl * C_ + ln] = f2bf(tile[ln][tl]);
  }
}

// ---------------- GEMM1: 256x256, BK=64, 8 waves, 1 barrier/K-tile -----------------
// De-lockstepped: per tile {read B(8)+A01(8); lgkm(4); MFMA ph0; stage B(t+1)x4;
// readA ph2; lgkm(4); MFMA ph1; stage A(t+1)x4; readA ph3; lgkm(4); MFMA ph2;
// lgkm(0); MFMA ph3; vmcnt(0); s_barrier}. Counted in-order lgkmcnt pipelines
// LDS reads one phase ahead of MFMA; no inter-phase barriers -> waves de-phase.
// gload_lds counts in vmcnt, ds_read in lgkmcnt (disjoint counters).
// WAR-safe: any wave past bar(t) has lgkm(0)-drained its reads of buffer de.
__global__ __launch_bounds__(512, 2) void gemm1_kernel(
    const u16* __restrict__ W, const u16* __restrict__ Xt,
    const float* __restrict__ b1, u16* __restrict__ Zt,
    const int* __restrict__ dptr)
{
  __shared__ __align__(16) u16 smem[65536];   // 128 KB: A0 A1 B0 B1 (32 KB each)
  const int dcap = *dptr;
  const int tid = threadIdx.x;
  const int lane = tid & 63, wave = tid >> 6;
  const int wm = wave >> 2, wn = wave & 3;    // 2 x 4 waves -> 128x64 per wave
  const int lp = lane & 15, lg = lane >> 4, lx = lane & 7;

  const int bid = blockIdx.x;
  const int xcd = bid & 7;
  const int idx = bid >> 3;                 // 0..127 within XCD
  const int mt  = idx & 3;                  // m fastest -> B-panel L2 reuse
  const int nt  = (xcd << 5) | (idx >> 2);  // n-tile 0..255
  const int m0  = mt * 256;
  const int n0g = nt * 256;
  const int b = n0g >> 13, t0 = n0g & (T_ - 1);
  const size_t xtb = (size_t)b * (T_ + DPAD) * C_;

  const int srl = tid >> 3;                 // stage row-in-quarter 0..63
  const int skb = tid & 7;                  // stage 16B-block 0..7
  const int sxk = (skb ^ (srl & 7)) << 3;   // swizzled k-elem offset 0..56

  f32x4 acc[8][4];
#pragma unroll
  for (int i = 0; i < 8; ++i)
#pragma unroll
    for (int j = 0; j < 4; ++j) acc[i][j] = (f32x4){0.f, 0.f, 0.f, 0.f};

#define SQA(kt_, dd, q_) do {                                                  \
    const int row_ = (q_) * 64 + srl;                                          \
    gload_lds16(W + (size_t)(m0 + row_) * 1024 + (kt_) * 64 + sxk,             \
                smem + (dd) * 16384 + (q_) * 4096 + tid * 8);                  \
  } while (0)

#define SQB(kt_, dd, q_) do {                                                  \
    const int row_ = (q_) * 64 + srl;                                          \
    const int kg_  = (kt_) * 64 + sxk;                                         \
    const int rsh_ = (kg_ >= 512) ? dcap : 0;                                  \
    gload_lds16(Xt + xtb + (size_t)(DPAD + t0 + row_ - rsh_) * C_ + (kg_ & 511), \
                smem + 32768 + (dd) * 16384 + (q_) * 4096 + tid * 8);          \
  } while (0)

#define LDA_(Ab_, f_, kk_) \
  (*(const bf16x8*)((Ab_) + (size_t)(wm * 128 + (f_) * 16 + lp) * 64 + ((((kk_) * 4 + lg) ^ lx) << 3)))
#define LDB_(Bb_, j_, kk_) \
  (*(const bf16x8*)((Bb_) + (size_t)(wn * 64 + (j_) * 16 + lp) * 64 + ((((kk_) * 4 + lg) ^ lx) << 3)))

// read the 4 A-frags for phase p (rows 2p,2p+1) into a[0..3]
#define READA(a_, p_, Ab_) do {                                                \
    a_[0] = LDA_(Ab_, 2 * (p_), 0);  a_[1] = LDA_(Ab_, 2 * (p_), 1);           \
    a_[2] = LDA_(Ab_, 2 * (p_) + 1, 0); a_[3] = LDA_(Ab_, 2 * (p_) + 1, 1);    \
  } while (0)

// 16 MFMA for phase p from a[0..3] x bfr; kk-outer -> acc dep distance 8
#define MFMAPH(a_, p_) do {                                                    \
    __builtin_amdgcn_s_setprio(1);                                             \
    _Pragma("unroll") for (int kk_ = 0; kk_ < 2; ++kk_) {                      \
      _Pragma("unroll") for (int j_ = 0; j_ < 4; ++j_)                         \
        acc[2*(p_)][j_]   = __builtin_amdgcn_mfma_f32_16x16x32_bf16(a_[kk_],     bfr[j_][kk_], acc[2*(p_)][j_],   0, 0, 0); \
      _Pragma("unroll") for (int j_ = 0; j_ < 4; ++j_)                         \
        acc[2*(p_)+1][j_] = __builtin_amdgcn_mfma_f32_16x16x32_bf16(a_[2 + kk_], bfr[j_][kk_], acc[2*(p_)+1][j_], 0, 0, 0); \
    }                                                                          \
    __builtin_amdgcn_s_setprio(0);                                             \
  } while (0)

#define LGKM(n_) do { asm volatile("s_waitcnt lgkmcnt(" #n_ ")" ::: "memory"); \
                      __builtin_amdgcn_sched_barrier(0); } while (0)
#define VMW(n_)  do { asm volatile("s_waitcnt vmcnt(" #n_ ")" ::: "memory");   \
                      __builtin_amdgcn_sched_barrier(0); } while (0)

  bf16x8 bfr[4][2];
  bf16x8 aW[4], aX[4];

  // prologue: stage tile 0 into buf 0, full drain, publish
  SQB(0, 0, 0); SQB(0, 0, 1); SQB(0, 0, 2); SQB(0, 0, 3);
  SQA(0, 0, 0); SQA(0, 0, 1); SQA(0, 0, 2); SQA(0, 0, 3);
  VMW(0);
  __builtin_amdgcn_s_barrier();

  for (int t = 0; t < 15; ++t) {
    const int dd = t & 1, de = dd ^ 1;
    const u16* Ab = smem + dd * 16384;
    const u16* Bb = smem + 32768 + dd * 16384;
    // issue B(8) + A-ph0(4) + A-ph1(4)
#pragma unroll
    for (int j = 0; j < 4; ++j) { bfr[j][0] = LDB_(Bb, j, 0); bfr[j][1] = LDB_(Bb, j, 1); }
    READA(aW, 0, Ab);
    READA(aX, 1, Ab);
    LGKM(4);                 // B + aW ready; aX in flight
    MFMAPH(aW, 0);
    SQB(t + 1, de, 0); SQB(t + 1, de, 1); SQB(t + 1, de, 2); SQB(t + 1, de, 3);
    READA(aW, 2, Ab);        // outstanding ds: aX(4) + aW'(4)
    LGKM(4);                 // aX ready
    MFMAPH(aX, 1);
    SQA(t + 1, de, 0); SQA(t + 1, de, 1); SQA(t + 1, de, 2); SQA(t + 1, de, 3);
    READA(aX, 3, Ab);        // outstanding ds: aW'(4) + aX'(4)
    LGKM(4);                 // aW' ready
    MFMAPH(aW, 2);
    LGKM(0);                 // aX' ready
    MFMAPH(aX, 3);
    VMW(0);                  // all 8 stages of t+1 landed (youngest ~2 phases old)
    __builtin_amdgcn_s_barrier();
  }
  {  // tile 15 (buf 1), no staging
    const u16* Ab = smem + 16384;
    const u16* Bb = smem + 49152;
#pragma unroll
    for (int j = 0; j < 4; ++j) { bfr[j][0] = LDB_(Bb, j, 0); bfr[j][1] = LDB_(Bb, j, 1); }
    READA(aW, 0, Ab);
    READA(aX, 1, Ab);
    LGKM(4);
    MFMAPH(aW, 0);
    READA(aW, 2, Ab);
    LGKM(4);
    MFMAPH(aX, 1);
    READA(aX, 3, Ab);
    LGKM(4);
    MFMAPH(aW, 2);
    LGKM(0);
    MFMAPH(aX, 3);
  }

  // epilogue: rows R..R+3 = (filter c0, gate c0, filter c0+1, gate c0+1)
  const int g4 = lane >> 4, p = lane & 15;
#pragma unroll
  for (int i = 0; i < 8; ++i) {
    const int R = m0 + wm * 128 + i * 16 + (g4 << 2);
    const float bi0 = b1[R], bi1 = b1[R + 1], bi2 = b1[R + 2], bi3 = b1[R + 3];
    const int c0 = R >> 1;
#pragma unroll
    for (int j = 0; j < 4; ++j) {
      const int ttc = t0 + wn * 64 + j * 16 + p;
      f32x4 v = acc[i][j];
      float z0 = tanh_(v[0] + bi0) * sigm_(v[1] + bi1);
      float z1 = tanh_(v[2] + bi2) * sigm_(v[3] + bi3);
      u32 pk = (u32)f2bf(z0) | ((u32)f2bf(z1) << 16);
      *(u32*)(Zt + (size_t)(b * T_ + ttc) * C_ + c0) = pk;
    }
  }
#undef SQA
#undef SQB
#undef LDA_
#undef LDB_
#undef READA
#undef MFMAPH
#undef LGKM
#undef VMW
}

// ---------------- GEMM2: [768x512] x z + residual/skip epilogue ----------------
// k-loop: proven drain structure. Epilogue: per-wave LDS transpose in disjoint
// region -> f32x4 coalesced x-loads / out-stores along t.
__global__ __launch_bounds__(256, 4) void gemm2_kernel(
    const u16* __restrict__ W2, const u16* __restrict__ Zt,
    const float* __restrict__ b2, const float* __restrict__ x,
    float* __restrict__ out)
{
  __shared__ __align__(16) u16 As[128 * 32];
  __shared__ __align__(16) u16 Bs[128 * 32];
  __shared__ __align__(16) float fstall[4 * 1088];   // 4 waves x 16x68 padded
  const int tid = threadIdx.x;
  const int lane = tid & 63, wave = tid >> 6;
  const int wm = wave >> 1, wn = wave & 1;

  const int bid = blockIdx.x;
  const int xcd = bid & 7;
  const int idx = bid >> 3;            // 0..383
  const int mt  = idx % 6;
  const int nt  = (xcd << 6) + idx / 6;
  const int m0 = mt * 128;
  const int n0g = nt * 128;
  const int b = n0g >> 13, t0 = n0g & (T_ - 1);
  const int srow = tid >> 2;
  const int skk  = (tid & 3) * 8;

  f32x4 acc[4][4];
#pragma unroll
  for (int i = 0; i < 4; ++i)
#pragma unroll
    for (int j = 0; j < 4; ++j) acc[i][j] = (f32x4){0.f, 0.f, 0.f, 0.f};

  const int aoff = (wm * 64 + (lane & 15)) * 32 + (lane >> 4) * 8;
  const int boff = (wn * 64 + (lane & 15)) * 32 + (lane >> 4) * 8;
  const size_t ztb = (size_t)b * T_ * C_;

  for (int kc = 0; kc < 16; ++kc) {
    const int k = kc * 32 + skk;        // 0..511
    const u16* gA = W2 + (size_t)(m0 + srow) * 512 + k;
    const u16* gB = Zt + ztb + (size_t)(t0 + srow) * C_ + k;
    gload_lds16(gA,            As + tid * 8);
    gload_lds16(gA + 64 * 512, As + 2048 + tid * 8);
    gload_lds16(gB,            Bs + tid * 8);
    gload_lds16(gB + 64 * C_,  Bs + 2048 + tid * 8);
    asm volatile("s_waitcnt vmcnt(0)" ::: "memory");
    __syncthreads();
    bf16x8 af[4], bfr[4];
#pragma unroll
    for (int i = 0; i < 4; ++i) af[i]  = *(const bf16x8*)(As + aoff + i * 512);
#pragma unroll
    for (int j = 0; j < 4; ++j) bfr[j] = *(const bf16x8*)(Bs + boff + j * 512);
#pragma unroll
    for (int i = 0; i < 4; ++i)
#pragma unroll
      for (int j = 0; j < 4; ++j)
        acc[i][j] = __builtin_amdgcn_mfma_f32_16x16x32_bf16(af[i], bfr[j], acc[i][j], 0, 0, 0);
    __syncthreads();
  }

  // ---- coalesced epilogue: per-wave private LDS transpose of 16x64 quadrants ----
  float* const fst = fstall + wave * 1088;         // 16 rows x 68 (padded)
  const int g = lane >> 4, p = lane & 15;
  const bool isres = (m0 < 512);

#pragma unroll
  for (int i = 0; i < 4; ++i) {
#pragma unroll
    for (int j = 0; j < 4; ++j)
#pragma unroll
      for (int r = 0; r < 4; ++r)
        fst[(g * 4 + r) * 68 + j * 16 + p] = acc[i][j][r];
#pragma unroll
    for (int q = 0; q < 4; ++q) {
      const int lrow = q * 4 + g;                  // 0..15
      const int row = m0 + wm * 64 + i * 16 + lrow;
      const int t = t0 + wn * 64 + p * 4;
      f32x4 v = *(const f32x4*)&fst[lrow * 68 + p * 4];
      const float bias = b2[row];
      f32x4 res;
      if (isres) {
        const size_t o = ((size_t)(b * 512 + row)) * T_ + t;
        f32x4 xv = *(const f32x4*)(x + o);
#pragma unroll
        for (int e = 0; e < 4; ++e)
          res[e] = (xv[e] + v[e] + bias) * 0.70710678118654752f;
        *(f32x4*)(out + o) = res;
      } else {
        const size_t o = (size_t)33554432 + ((size_t)(b * 256 + (row - 512))) * T_ + t;
#pragma unroll
        for (int e = 0; e < 4; ++e)
          res[e] = v[e] + bias;
        *(f32x4*)(out + o) = res;
      }
    }
  }
}

extern "C" void kernel_launch(void* const* d_in, const int* in_sizes, int n_in,
                              void* d_out, int out_size, void* d_ws, size_t ws_size,
                              hipStream_t stream) {
  const float* x  = (const float*)d_in[0];
  const float* fw = (const float*)d_in[1];
  const float* fb = (const float*)d_in[2];
  const float* gw = (const float*)d_in[3];
  const float* gb = (const float*)d_in[4];
  const float* rw = (const float*)d_in[5];
  const float* rb = (const float*)d_in[6];
  const float* sw = (const float*)d_in[7];
  const float* sb = (const float*)d_in[8];
  const int* dil  = (const int*)d_in[9];

  char* ws = (char*)d_ws;
  u16*   Wbig = (u16*)(ws + OFF_WBIG);
  u16*   W2   = (u16*)(ws + OFF_W2);
  float* b1   = (float*)(ws + OFF_B1);
  float* b2   = (float*)(ws + OFF_B2);
  u16*   Xt   = (u16*)(ws + OFF_XT);
  u16*   Zt   = (u16*)(ws + OFF_ZT);
  float* out  = (float*)d_out;

  hipLaunchKernelGGL(pack_kernel, dim3(5767), dim3(256), 0, stream,
                     fw, fb, gw, gb, rw, rb, sw, sb, Wbig, W2, b1, b2, Xt);
  hipLaunchKernelGGL(transpose_kernel, dim3(8192), dim3(256), 0, stream, x, Xt);
  hipLaunchKernelGGL(gemm1_kernel, dim3(1024), dim3(512), 0, stream, Wbig, Xt, b1, Zt, dil);
  hipLaunchKernelGGL(gemm2_kernel, dim3(3072), dim3(256), 0, stream, W2, Zt, b2, x, out);
}

// Round 11
// 305.776 us; speedup vs baseline: 1.7808x; 1.0053x over previous
//
#include <hip/hip_runtime.h>
#include <hip/hip_bf16.h>

typedef __attribute__((ext_vector_type(4))) float f32x4;
typedef __attribute__((ext_vector_type(8))) short bf16x8;
typedef unsigned int   u32;
typedef unsigned short u16;

#define DPAD 8
#define B_   8
#define C_   512
#define T_   8192
#define S_   256

// workspace byte offsets
#define OFF_WBIG 0u          // u16[1024*1024]      = 2,097,152 B
#define OFF_W2   2097152u    // u16[768*512]        =   786,432 B
#define OFF_B1   2883584u    // float[1024]
#define OFF_B2   2887680u    // float[768]
#define OFF_XT   2891776u    // u16[8*(8192+8)*512] = 67,174,400 B
#define OFF_ZT   70066176u   // u16[8*8192*512]     = 67,108,864 B

__device__ __forceinline__ u16 f2bf(float f) {
  u32 u = __builtin_bit_cast(u32, f);
  u += 0x7FFFu + ((u >> 16) & 1u);
  return (u16)(u >> 16);
}
__device__ __forceinline__ float sigm_(float x) { return 1.0f / (1.0f + __expf(-x)); }
__device__ __forceinline__ float tanh_(float x) { return 2.0f / (1.0f + __expf(-2.0f * x)) - 1.0f; }

__device__ __forceinline__ void gload_lds16(const void* g, void* l) {
  __builtin_amdgcn_global_load_lds(
      (const __attribute__((address_space(1))) void*)g,
      (__attribute__((address_space(3))) void*)l, 16, 0, 0);
}

// ---------------- pack weights / biases, zero Xt pad rows ----------------
__global__ void pack_kernel(const float* __restrict__ fw, const float* __restrict__ fb,
                            const float* __restrict__ gw, const float* __restrict__ gb,
                            const float* __restrict__ rw, const float* __restrict__ rb,
                            const float* __restrict__ sw, const float* __restrict__ sb,
                            u16* __restrict__ Wbig, u16* __restrict__ W2,
                            float* __restrict__ b1, float* __restrict__ b2,
                            u16* __restrict__ Xt)
{
  int idx = blockIdx.x * 256 + threadIdx.x;
  if (idx < 1048576) {                    // Wbig[row][k], row 2i=filter i, 2i+1=gate i
    int row = idx >> 10, k = idx & 1023;  // k<512: tap1 (x[t]); k>=512: tap0 (x[t-d])
    int i = row >> 1;
    const float* src = (row & 1) ? gw : fw;
    float v = src[((i << 9) + (k & 511)) * 2 + ((k < 512) ? 1 : 0)];
    Wbig[idx] = f2bf(v);
    return;
  }
  idx -= 1048576;
  if (idx < 393216) {                     // W2[r][k]: r<512 res, else skip
    int r = idx >> 9, k = idx & 511;
    float v = (r < 512) ? rw[(r << 9) + k] : sw[((r - 512) << 9) + k];
    W2[idx] = f2bf(v);
    return;
  }
  idx -= 393216;
  if (idx < 1024) { b1[idx] = (idx & 1) ? gb[idx >> 1] : fb[idx >> 1]; return; }
  idx -= 1024;
  if (idx < 768) { b2[idx] = (idx < 512) ? rb[idx] : sb[idx - 512]; return; }
  idx -= 768;
  if (idx < B_ * DPAD * C_) {             // zero causal pad rows of Xt
    int b = idx >> 12;                    // DPAD*C_ = 4096
    int rest = idx & 4095;
    Xt[(size_t)b * (T_ + DPAD) * C_ + rest] = 0;
  }
}

// ---------------- x [B][C][T] f32 -> Xt [B][DPAD+T][C] bf16 ----------------
__global__ __launch_bounds__(256) void transpose_kernel(const float* __restrict__ x,
                                                        u16* __restrict__ Xt)
{
  __shared__ float tile[64][65];
  int bid = blockIdx.x;
  int ct = bid & 7, tt = (bid >> 3) & 127, b = bid >> 10;
  int w = threadIdx.x >> 6, ln = threadIdx.x & 63;
  const float* xp = x + ((size_t)(b * C_ + ct * 64)) * T_ + tt * 64;
#pragma unroll
  for (int r = 0; r < 16; ++r) {
    int cl = r * 4 + w;
    tile[cl][ln] = xp[(size_t)cl * T_ + ln];
  }
  __syncthreads();
  u16* op = Xt + ((size_t)b * (T_ + DPAD) + DPAD + tt * 64) * C_ + ct * 64;
#pragma unroll
  for (int r = 0; r < 16; ++r) {
    int tl = r * 4 + w;
    op[(size_t)tl * C_ + ln] = f2bf(tile[ln][tl]);
  }
}

// ---------------- GEMM1: 256x256, BK=64, 8 waves, 1 barrier/K-tile, 0 addr-VALU ----
// Sync skeleton identical to the proven round-10 kernel. All 15 K-tiles fully
// unrolled with literal t: ds_read addresses = hoisted lane base + constant GEP
// (folds to ds_read offset imm); stage addresses = hoisted quarter base +
// literal kt*64 (folds to global_load_lds offset imm). Tap switch at kt=8 is
// thread-uniform -> compile-time base selection (B2 = B1 - d*C - 512).
__global__ __launch_bounds__(512, 2) void gemm1_kernel(
    const u16* __restrict__ W, const u16* __restrict__ Xt,
    const float* __restrict__ b1, u16* __restrict__ Zt,
    const int* __restrict__ dptr)
{
  __shared__ __align__(16) u16 smem[65536];   // 128 KB: [A0|A1|B0|B1] 16384 u16 each
  const int dcap = *dptr;
  const int tid = threadIdx.x;
  const int lane = tid & 63, wave = tid >> 6;
  const int wm = wave >> 2, wn = wave & 3;    // 2 x 4 waves -> 128x64 per wave
  const int lp = lane & 15, lg = lane >> 4, lx = lane & 7;

  const int bid = blockIdx.x;
  const int xcd = bid & 7;
  const int idx = bid >> 3;                 // 0..127 within XCD
  const int mt  = idx & 3;                  // m fastest -> B-panel L2 reuse
  const int nt  = (xcd << 5) | (idx >> 2);  // n-tile 0..255
  const int m0  = mt * 256;
  const int n0g = nt * 256;
  const int b = n0g >> 13, t0 = n0g & (T_ - 1);
  const size_t xtb = (size_t)b * (T_ + DPAD) * C_;

  const int srl = tid >> 3;                 // stage row-in-quarter 0..63
  const int skb = tid & 7;                  // stage 16B-block 0..7
  const int sxk = (skb ^ (srl & 7)) << 3;   // swizzled k-elem offset 0..56

  f32x4 acc[8][4];
#pragma unroll
  for (int i = 0; i < 8; ++i)
#pragma unroll
    for (int j = 0; j < 4; ++j) acc[i][j] = (f32x4){0.f, 0.f, 0.f, 0.f};

  // ---- hoisted stage bases (global) and dests (LDS), all literal-indexed ----
  const u16* gAq[4];  const u16* gB1q[4]; const u16* gB2q[4];
  u16* dAq[2][4];     u16* dBq[2][4];
#pragma unroll
  for (int q = 0; q < 4; ++q) {
    const int row = q * 64 + srl;
    gAq[q]  = W + (size_t)(m0 + row) * 1024 + sxk;
    const u16* bb = Xt + xtb + (size_t)(DPAD + t0 + row) * C_ + sxk;
    gB1q[q] = bb;                                   // tap1: +kt*64, kt=0..7
    gB2q[q] = bb - (size_t)dcap * C_ - 512;         // tap0: +kt*64, kt=8..15
#pragma unroll
    for (int d = 0; d < 2; ++d) {
      dAq[d][q] = smem + d * 16384 + q * 4096 + tid * 8;
      dBq[d][q] = smem + 32768 + d * 16384 + q * 4096 + tid * 8;
    }
  }
  // ---- hoisted ds_read lane bases (kk in {0,1}); frag/parity via constant GEP ----
  const int blk0 = ((0 * 4 + lg) ^ lx) << 3;
  const int blk1 = ((1 * 4 + lg) ^ lx) << 3;
  const u16* const ArdB0 = smem + (size_t)(wm * 128 + lp) * 64 + blk0;
  const u16* const ArdB1 = smem + (size_t)(wm * 128 + lp) * 64 + blk1;
  const u16* const BrdB0 = smem + 32768 + (size_t)(wn * 64 + lp) * 64 + blk0;
  const u16* const BrdB1 = smem + 32768 + (size_t)(wn * 64 + lp) * 64 + blk1;

#define GL16(g_, l_) __builtin_amdgcn_global_load_lds(                         \
    (const __attribute__((address_space(1))) void*)(g_),                       \
    (__attribute__((address_space(3))) void*)(l_), 16, 0, 0)

#define SQA_(kt_, de_) do {                                                    \
    GL16(gAq[0] + (kt_) * 64, dAq[de_][0]);                                    \
    GL16(gAq[1] + (kt_) * 64, dAq[de_][1]);                                    \
    GL16(gAq[2] + (kt_) * 64, dAq[de_][2]);                                    \
    GL16(gAq[3] + (kt_) * 64, dAq[de_][3]);                                    \
  } while (0)

#define SQB_(kt_, de_) do {                                                    \
    GL16(((kt_) < 8 ? gB1q[0] : gB2q[0]) + (kt_) * 64, dBq[de_][0]);           \
    GL16(((kt_) < 8 ? gB1q[1] : gB2q[1]) + (kt_) * 64, dBq[de_][1]);           \
    GL16(((kt_) < 8 ? gB1q[2] : gB2q[2]) + (kt_) * 64, dBq[de_][2]);           \
    GL16(((kt_) < 8 ? gB1q[3] : gB2q[3]) + (kt_) * 64, dBq[de_][3]);           \
  } while (0)

#define RDB(dd_) do {                                                          \
    _Pragma("unroll") for (int j_ = 0; j_ < 4; ++j_) {                         \
      bfr[j_][0] = *(const bf16x8*)(BrdB0 + (dd_) * 16384 + j_ * 1024);        \
      bfr[j_][1] = *(const bf16x8*)(BrdB1 + (dd_) * 16384 + j_ * 1024);        \
    }                                                                          \
  } while (0)

#define RDA(a_, p_, dd_) do {                                                  \
    a_[0] = *(const bf16x8*)(ArdB0 + (dd_) * 16384 + (2 * (p_)) * 1024);       \
    a_[1] = *(const bf16x8*)(ArdB1 + (dd_) * 16384 + (2 * (p_)) * 1024);       \
    a_[2] = *(const bf16x8*)(ArdB0 + (dd_) * 16384 + (2 * (p_) + 1) * 1024);   \
    a_[3] = *(const bf16x8*)(ArdB1 + (dd_) * 16384 + (2 * (p_) + 1) * 1024);   \
  } while (0)

#define MFMAPH(a_, p_) do {                                                    \
    __builtin_amdgcn_s_setprio(1);                                             \
    _Pragma("unroll") for (int kk_ = 0; kk_ < 2; ++kk_) {                      \
      _Pragma("unroll") for (int j_ = 0; j_ < 4; ++j_)                         \
        acc[2*(p_)][j_]   = __builtin_amdgcn_mfma_f32_16x16x32_bf16(a_[kk_],     bfr[j_][kk_], acc[2*(p_)][j_],   0, 0, 0); \
      _Pragma("unroll") for (int j_ = 0; j_ < 4; ++j_)                         \
        acc[2*(p_)+1][j_] = __builtin_amdgcn_mfma_f32_16x16x32_bf16(a_[2 + kk_], bfr[j_][kk_], acc[2*(p_)+1][j_], 0, 0, 0); \
    }                                                                          \
    __builtin_amdgcn_s_setprio(0);                                             \
  } while (0)

#define LGKM(n_) do { asm volatile("s_waitcnt lgkmcnt(" #n_ ")" ::: "memory"); \
                      __builtin_amdgcn_sched_barrier(0); } while (0)
#define VMW(n_)  do { asm volatile("s_waitcnt vmcnt(" #n_ ")" ::: "memory");   \
                      __builtin_amdgcn_sched_barrier(0); } while (0)

// one K-tile, literal t_ (0..14): sync skeleton identical to round 10
#define BODY(t_) do {                                                          \
    RDB((t_) & 1);                                                             \
    RDA(aW, 0, (t_) & 1);                                                      \
    RDA(aX, 1, (t_) & 1);                                                      \
    LGKM(4); MFMAPH(aW, 0);                                                    \
    SQB_((t_) + 1, ((t_) & 1) ^ 1);                                            \
    RDA(aW, 2, (t_) & 1);                                                      \
    LGKM(4); MFMAPH(aX, 1);                                                    \
    SQA_((t_) + 1, ((t_) & 1) ^ 1);                                            \
    RDA(aX, 3, (t_) & 1);                                                      \
    LGKM(4); MFMAPH(aW, 2);                                                    \
    LGKM(0); MFMAPH(aX, 3);                                                    \
    VMW(0);                                                                    \
    __builtin_amdgcn_s_barrier();                                              \
  } while (0)

  bf16x8 bfr[4][2];
  bf16x8 aW[4], aX[4];

  // prologue: stage tile 0 into buf 0, full drain, publish
  SQB_(0, 0); SQA_(0, 0);
  VMW(0);
  __builtin_amdgcn_s_barrier();

  BODY(0);  BODY(1);  BODY(2);  BODY(3);  BODY(4);
  BODY(5);  BODY(6);  BODY(7);  BODY(8);  BODY(9);
  BODY(10); BODY(11); BODY(12); BODY(13); BODY(14);

  {  // tile 15 (buf 1), no staging
    RDB(1);
    RDA(aW, 0, 1);
    RDA(aX, 1, 1);
    LGKM(4); MFMAPH(aW, 0);
    RDA(aW, 2, 1);
    LGKM(4); MFMAPH(aX, 1);
    RDA(aX, 3, 1);
    LGKM(4); MFMAPH(aW, 2);
    LGKM(0); MFMAPH(aX, 3);
  }

  // epilogue: rows R..R+3 = (filter c0, gate c0, filter c0+1, gate c0+1)
  const int g4 = lane >> 4, p = lane & 15;
#pragma unroll
  for (int i = 0; i < 8; ++i) {
    const int R = m0 + wm * 128 + i * 16 + (g4 << 2);
    const float bi0 = b1[R], bi1 = b1[R + 1], bi2 = b1[R + 2], bi3 = b1[R + 3];
    const int c0 = R >> 1;
#pragma unroll
    for (int j = 0; j < 4; ++j) {
      const int ttc = t0 + wn * 64 + j * 16 + p;
      f32x4 v = acc[i][j];
      float z0 = tanh_(v[0] + bi0) * sigm_(v[1] + bi1);
      float z1 = tanh_(v[2] + bi2) * sigm_(v[3] + bi3);
      u32 pk = (u32)f2bf(z0) | ((u32)f2bf(z1) << 16);
      *(u32*)(Zt + (size_t)(b * T_ + ttc) * C_ + c0) = pk;
    }
  }
#undef GL16
#undef SQA_
#undef SQB_
#undef RDB
#undef RDA
#undef MFMAPH
#undef LGKM
#undef VMW
#undef BODY
}

// ---------------- GEMM2: [768x512] x z + residual/skip epilogue ----------------
// k-loop: proven drain structure. Epilogue: per-wave LDS transpose in disjoint
// region -> f32x4 coalesced x-loads / out-stores along t.
__global__ __launch_bounds__(256, 4) void gemm2_kernel(
    const u16* __restrict__ W2, const u16* __restrict__ Zt,
    const float* __restrict__ b2, const float* __restrict__ x,
    float* __restrict__ out)
{
  __shared__ __align__(16) u16 As[128 * 32];
  __shared__ __align__(16) u16 Bs[128 * 32];
  __shared__ __align__(16) float fstall[4 * 1088];   // 4 waves x 16x68 padded
  const int tid = threadIdx.x;
  const int lane = tid & 63, wave = tid >> 6;
  const int wm = wave >> 1, wn = wave & 1;

  const int bid = blockIdx.x;
  const int xcd = bid & 7;
  const int idx = bid >> 3;            // 0..383
  const int mt  = idx % 6;
  const int nt  = (xcd << 6) + idx / 6;
  const int m0 = mt * 128;
  const int n0g = nt * 128;
  const int b = n0g >> 13, t0 = n0g & (T_ - 1);
  const int srow = tid >> 2;
  const int skk  = (tid & 3) * 8;

  f32x4 acc[4][4];
#pragma unroll
  for (int i = 0; i < 4; ++i)
#pragma unroll
    for (int j = 0; j < 4; ++j) acc[i][j] = (f32x4){0.f, 0.f, 0.f, 0.f};

  const int aoff = (wm * 64 + (lane & 15)) * 32 + (lane >> 4) * 8;
  const int boff = (wn * 64 + (lane & 15)) * 32 + (lane >> 4) * 8;
  const size_t ztb = (size_t)b * T_ * C_;

  for (int kc = 0; kc < 16; ++kc) {
    const int k = kc * 32 + skk;        // 0..511
    const u16* gA = W2 + (size_t)(m0 + srow) * 512 + k;
    const u16* gB = Zt + ztb + (size_t)(t0 + srow) * C_ + k;
    gload_lds16(gA,            As + tid * 8);
    gload_lds16(gA + 64 * 512, As + 2048 + tid * 8);
    gload_lds16(gB,            Bs + tid * 8);
    gload_lds16(gB + 64 * C_,  Bs + 2048 + tid * 8);
    asm volatile("s_waitcnt vmcnt(0)" ::: "memory");
    __syncthreads();
    bf16x8 af[4], bfr[4];
#pragma unroll
    for (int i = 0; i < 4; ++i) af[i]  = *(const bf16x8*)(As + aoff + i * 512);
#pragma unroll
    for (int j = 0; j < 4; ++j) bfr[j] = *(const bf16x8*)(Bs + boff + j * 512);
#pragma unroll
    for (int i = 0; i < 4; ++i)
#pragma unroll
      for (int j = 0; j < 4; ++j)
        acc[i][j] = __builtin_amdgcn_mfma_f32_16x16x32_bf16(af[i], bfr[j], acc[i][j], 0, 0, 0);
    __syncthreads();
  }

  // ---- coalesced epilogue: per-wave private LDS transpose of 16x64 quadrants ----
  float* const fst = fstall + wave * 1088;         // 16 rows x 68 (padded)
  const int g = lane >> 4, p = lane & 15;
  const bool isres = (m0 < 512);

#pragma unroll
  for (int i = 0; i < 4; ++i) {
#pragma unroll
    for (int j = 0; j < 4; ++j)
#pragma unroll
      for (int r = 0; r < 4; ++r)
        fst[(g * 4 + r) * 68 + j * 16 + p] = acc[i][j][r];
#pragma unroll
    for (int q = 0; q < 4; ++q) {
      const int lrow = q * 4 + g;                  // 0..15
      const int row = m0 + wm * 64 + i * 16 + lrow;
      const int t = t0 + wn * 64 + p * 4;
      f32x4 v = *(const f32x4*)&fst[lrow * 68 + p * 4];
      const float bias = b2[row];
      f32x4 res;
      if (isres) {
        const size_t o = ((size_t)(b * 512 + row)) * T_ + t;
        f32x4 xv = *(const f32x4*)(x + o);
#pragma unroll
        for (int e = 0; e < 4; ++e)
          res[e] = (xv[e] + v[e] + bias) * 0.70710678118654752f;
        *(f32x4*)(out + o) = res;
      } else {
        const size_t o = (size_t)33554432 + ((size_t)(b * 256 + (row - 512))) * T_ + t;
#pragma unroll
        for (int e = 0; e < 4; ++e)
          res[e] = v[e] + bias;
        *(f32x4*)(out + o) = res;
      }
    }
  }
}

extern "C" void kernel_launch(void* const* d_in, const int* in_sizes, int n_in,
                              void* d_out, int out_size, void* d_ws, size_t ws_size,
                              hipStream_t stream) {
  const float* x  = (const float*)d_in[0];
  const float* fw = (const float*)d_in[1];
  const float* fb = (const float*)d_in[2];
  const float* gw = (const float*)d_in[3];
  const float* gb = (const float*)d_in[4];
  const float* rw = (const float*)d_in[5];
  const float* rb = (const float*)d_in[6];
  const float* sw = (const float*)d_in[7];
  const float* sb = (const float*)d_in[8];
  const int* dil  = (const int*)d_in[9];

  char* ws = (char*)d_ws;
  u16*   Wbig = (u16*)(ws + OFF_WBIG);
  u16*   W2   = (u16*)(ws + OFF_W2);
  float* b1   = (float*)(ws + OFF_B1);
  float* b2   = (float*)(ws + OFF_B2);
  u16*   Xt   = (u16*)(ws + OFF_XT);
  u16*   Zt   = (u16*)(ws + OFF_ZT);
  float* out  = (float*)d_out;

  hipLaunchKernelGGL(pack_kernel, dim3(5767), dim3(256), 0, stream,
                     fw, fb, gw, gb, rw, rb, sw, sb, Wbig, W2, b1, b2, Xt);
  hipLaunchKernelGGL(transpose_kernel, dim3(8192), dim3(256), 0, stream, x, Xt);
  hipLaunchKernelGGL(gemm1_kernel, dim3(1024), dim3(512), 0, stream, Wbig, Xt, b1, Zt, dil);
  hipLaunchKernelGGL(gemm2_kernel, dim3(3072), dim3(256), 0, stream, W2, Zt, b2, x, out);
}